// Round 3
// baseline (726.820 us; speedup 1.0000x reference)
//
#include <hip/hip_runtime.h>
#include <hip/hip_bf16.h>

typedef __bf16 bf16;
typedef __bf16 bf16x2 __attribute__((ext_vector_type(2)));
typedef __bf16 bf16x4 __attribute__((ext_vector_type(4)));
typedef __bf16 bf16x8 __attribute__((ext_vector_type(8)));
typedef float  f32x4  __attribute__((ext_vector_type(4)));

// tanh(x) = 1 - 2/(exp2(2*log2e*x)+1); v_exp_f32+v_rcp_f32, ~1e-6 abs err
__device__ __forceinline__ float fast_tanh(float x) {
  float e = __builtin_amdgcn_exp2f(x * 2.88539008177793f);
  return 1.f - 2.f * __builtin_amdgcn_rcpf(e + 1.f);
}

// Bank-conflict XOR swizzle for 8-elem (16B) slots: slot ^= row&7.  Applied to
// the LDS A-tile (written per-lane, read in the 16-rows-same-column MFMA
// pattern that is otherwise a 16-way conflict on 512B-stride rows).
__device__ __forceinline__ int swz(int elem, int row) {
  return elem ^ ((row & 7) << 3);
}

// ---------------- no-LDS 64x64-tile GEMM: C = act(alpha*(A@W^T)+bias) --------
// A:[M,K] bf16 rm, W:[N,K] bf16 rm.  All operand panels are L2/L3-resident
// (weights <=512KB, activations <=16MB), so LDS staging + barriers were pure
// overhead (guide common-mistake #7).  Fragments load straight from global:
// each wave instr reads 16 rows x 64B contiguous -> cacheline-clean.  Zero
// LDS, zero barriers; compiler software-pipelines the loads freely.
// 256 thr = 4 waves, each 32x32 via 2x2 MFMA.  ACT: 0 none, 1 tanh, 2 relu.
template<int ACT, typename OT>
__global__ __launch_bounds__(256, 4)
void gemm64(const bf16* __restrict__ A, const bf16* __restrict__ W,
            OT* __restrict__ C, int K, int ldc, float alpha,
            const float* __restrict__ bias) {
  const int tid  = threadIdx.x;
  const int wave = tid >> 6, lane = tid & 63;
  const int wr = wave >> 1, wc = wave & 1;
  const int g = lane >> 4, l4 = lane & 15;

  f32x4 acc[2][2];
#pragma unroll
  for (int i = 0; i < 2; ++i)
#pragma unroll
    for (int j = 0; j < 2; ++j)
      acc[i][j] = (f32x4){0.f, 0.f, 0.f, 0.f};

  // per-lane row bases: rows (wr*32 + i*16 + l4) of A, (wc*32 + j*16 + l4) of W
  const bf16* Ap = A + ((size_t)blockIdx.x * 64 + wr * 32 + l4) * K;
  const bf16* Wp = W + ((size_t)blockIdx.y * 64 + wc * 32 + l4) * K;

#pragma unroll 4
  for (int k0 = 0; k0 < K; k0 += 32) {   // K is a multiple of 128
    const int ko = k0 + g * 8;
    bf16x8 af[2], bfr[2];
    af[0]  = *(const bf16x8*)&Ap[ko];
    af[1]  = *(const bf16x8*)&Ap[(size_t)16 * K + ko];
    bfr[0] = *(const bf16x8*)&Wp[ko];
    bfr[1] = *(const bf16x8*)&Wp[(size_t)16 * K + ko];
#pragma unroll
    for (int i = 0; i < 2; ++i)
#pragma unroll
      for (int j = 0; j < 2; ++j)
        acc[i][j] = __builtin_amdgcn_mfma_f32_16x16x32_bf16(af[i], bfr[j], acc[i][j], 0, 0, 0);
  }

  const int rbase = blockIdx.x * 64 + wr * 32;
  const int cbase = blockIdx.y * 64 + wc * 32;
#pragma unroll
  for (int i = 0; i < 2; ++i)
#pragma unroll
    for (int j = 0; j < 2; ++j) {
      const int col = cbase + j * 16 + l4;
      const float bv = bias ? bias[col] : 0.f;
#pragma unroll
      for (int r = 0; r < 4; ++r) {
        const int row = rbase + i * 16 + g * 4 + r;
        float v = acc[i][j][r] * alpha + bv;
        if (ACT == 1) v = fast_tanh(v);
        if (ACT == 2) v = fmaxf(v, 0.f);
        C[(size_t)row * ldc + col] = (OT)v;
      }
    }
}

// ---------------- fused score + softmax + aggregate ----------------
// Per block: 64 A-rows = 4 nodes.  s[row] = scale * sum_{c<512} tanh((A@W^T)[row,c]) * y[node,c]
// then per-node masked softmax over the 16 rows, then agg[node,:] = sum_k w[k]*A[node*16+k,:].
// A (f32, streamed from HBM) is converted once into a persistent swizzled LDS
// bf16 tile, reused for both j-chunks and the aggregation.  W (256KB, shared
// by ALL blocks -> L2-resident) is NOT staged: B-fragments load directly from
// global into registers.  Main loop has no barriers; latency hides via
// 4 blocks/CU (16 waves) + compiler pipelining.
template<int D>
__global__ __launch_bounds__(256, 4)
void score_agg(const float* __restrict__ A, const bf16* __restrict__ Wb,
               const bf16* __restrict__ y, int ldy, int yoff, float scale,
               const int* __restrict__ mask, bf16* __restrict__ agg) {
  __shared__ bf16 As[64 * D];     // persistent block A-tile (bf16, swizzled)
  __shared__ float sred[256];     // per-wave row partials
  __shared__ float wgt[64];       // softmax weights
  const int tid  = threadIdx.x;
  const int wave = tid >> 6, lane = tid & 63;
  const int g = lane >> 4, l4 = lane & 15;
  const int blk = blockIdx.x;

  // ---- stage full 64xD A block: f32 global -> bf16 LDS (coalesced float4) ----
  const float* Ab = A + (size_t)blk * 64 * D;
  constexpr int F4PR = D / 4;
#pragma unroll
  for (int ii = 0; ii < D / 16; ++ii) {
    const int c    = ii * 256 + tid;
    const int row  = c / F4PR;
    const int col4 = (c % F4PR) * 4;
    const float4 v = *(const float4*)(Ab + (size_t)row * D + col4);
    bf16x4 o = {(bf16)v.x, (bf16)v.y, (bf16)v.z, (bf16)v.w};
    *(bf16x4*)&As[row * D + swz(col4, row)] = o;
  }

  float p[4][4];
#pragma unroll
  for (int i = 0; i < 4; ++i)
#pragma unroll
    for (int r = 0; r < 4; ++r) p[i][r] = 0.f;

  __syncthreads();

  constexpr int NP = D / 32;               // MFMA phases per 256-col chunk
  for (int j = 0; j < 2; ++j) {            // H-chunk of 256 cols
    const bf16* Wj = Wb + (size_t)j * 256 * D;
    f32x4 acc[4][4];
#pragma unroll
    for (int i = 0; i < 4; ++i)
#pragma unroll
      for (int jj = 0; jj < 4; ++jj)
        acc[i][jj] = (f32x4){0.f, 0.f, 0.f, 0.f};

#pragma unroll
    for (int ph = 0; ph < NP; ++ph) {
      const int ka = ph * 32 + g * 8;
      bf16x8 af[4], bfr[4];
#pragma unroll
      for (int i = 0; i < 4; ++i) {
        const int ra = i * 16 + l4;
        af[i] = *(const bf16x8*)&As[ra * D + swz(ka, ra)];
      }
#pragma unroll
      for (int jj = 0; jj < 4; ++jj) {
        const int rb = wave * 64 + jj * 16 + l4;   // W row within chunk
        bfr[jj] = *(const bf16x8*)&Wj[(size_t)rb * D + ka];
      }
#pragma unroll
      for (int i = 0; i < 4; ++i)
#pragma unroll
        for (int jj = 0; jj < 4; ++jj)
          acc[i][jj] = __builtin_amdgcn_mfma_f32_16x16x32_bf16(af[i], bfr[jj], acc[i][jj], 0, 0, 0);
    }

    // fold chunk into per-lane score partials (rows i*16.. all belong to node i)
#pragma unroll
    for (int i = 0; i < 4; ++i) {
      const size_t yb = (size_t)(blk * 4 + i) * ldy + yoff + j * 256 + wave * 64;
#pragma unroll
      for (int jj = 0; jj < 4; ++jj) {
        const float yv = (float)y[yb + jj * 16 + l4];
        p[i][0] += fast_tanh(acc[i][jj][0]) * yv;
        p[i][1] += fast_tanh(acc[i][jj][1]) * yv;
        p[i][2] += fast_tanh(acc[i][jj][2]) * yv;
        p[i][3] += fast_tanh(acc[i][jj][3]) * yv;
      }
    }
  }

  // reduce over the 16 l4-lanes; lane l4==0 of each g-group holds the wave partial
#pragma unroll
  for (int i = 0; i < 4; ++i)
#pragma unroll
    for (int r = 0; r < 4; ++r) {
      float v = p[i][r];
#pragma unroll
      for (int m = 1; m < 16; m <<= 1) v += __shfl_xor(v, m);
      p[i][r] = v;
    }
  if (l4 == 0) {
#pragma unroll
    for (int i = 0; i < 4; ++i)
#pragma unroll
      for (int r = 0; r < 4; ++r)
        sred[wave * 64 + i * 16 + g * 4 + r] = p[i][r];
  }
  __syncthreads();

  // ---- per-node masked softmax over 16 rows (threads 0..63 = wave 0) ----
  if (tid < 64) {
    const int node_g = blk * 4 + (tid >> 4);
    float s = (sred[tid] + sred[64 + tid] + sred[128 + tid] + sred[192 + tid]) * scale;
    if (mask) s -= 9999999.0f * (float)mask[node_g * 16 + (tid & 15)];
    float m = s;
#pragma unroll
    for (int d = 1; d < 16; d <<= 1) m = fmaxf(m, __shfl_xor(m, d));
    float e = __builtin_amdgcn_exp2f((s - m) * 1.44269504088896f);
    float sum = e;
#pragma unroll
    for (int d = 1; d < 16; d <<= 1) sum += __shfl_xor(sum, d);
    wgt[tid] = e / sum;
  }
  __syncthreads();

  // ---- aggregate from the LDS A-tile: agg[node,d] = sum_k wgt[k]*As[node*16+k, d] ----
  constexpr int EPT = D / 64;              // elems per thread (4 for D=256, 2 for D=128)
  const int n  = tid >> 6;                 // local node
  const int dl = (tid & 63) * EPT;
  float a[EPT];
#pragma unroll
  for (int e = 0; e < EPT; ++e) a[e] = 0.f;
#pragma unroll
  for (int k = 0; k < 16; ++k) {
    const float w = wgt[n * 16 + k];
    const int rk = n * 16 + k;
    if constexpr (EPT == 4) {
      bf16x4 v = *(const bf16x4*)&As[rk * D + swz(dl, rk)];
      a[0] += w * (float)v[0]; a[1] += w * (float)v[1];
      a[2] += w * (float)v[2]; a[3] += w * (float)v[3];
    } else {
      bf16x2 v = *(const bf16x2*)&As[rk * D + swz(dl, rk)];
      a[0] += w * (float)v[0]; a[1] += w * (float)v[1];
    }
  }
  if constexpr (EPT == 4) {
    bf16x4 o = {(bf16)a[0], (bf16)a[1], (bf16)a[2], (bf16)a[3]};
    *(bf16x4*)&agg[(size_t)(blk * 4 + n) * D + dl] = o;
  } else {
    bf16x2 o = {(bf16)a[0], (bf16)a[1]};
    *(bf16x2*)&agg[(size_t)(blk * 4 + n) * D + dl] = o;
  }
}

// batched f32->bf16 conversion (x + 7 weight matrices); all sizes % 2048 == 0
struct CvtEnt { const float* s; bf16* d; int n; };
struct CvtArgs { CvtEnt e[8]; };

__global__ void cvt_small(CvtArgs args) {
  const CvtEnt ent = args.e[blockIdx.y];
  const int i = blockIdx.x * 2048 + threadIdx.x * 8;
  if (i < ent.n) {
    const float4 a = *(const float4*)(ent.s + i);
    const float4 c = *(const float4*)(ent.s + i + 4);
    bf16x8 o = { (bf16)a.x, (bf16)a.y, (bf16)a.z, (bf16)a.w,
                 (bf16)c.x, (bf16)c.y, (bf16)c.z, (bf16)c.w };
    *(bf16x8*)(ent.d + i) = o;
  }
}

// fused 512x512 transpose + f32->bf16 for both W2 matrices (z selects)
__global__ void transpose2(const float* __restrict__ s0, bf16* __restrict__ d0,
                           const float* __restrict__ s1, bf16* __restrict__ d1) {
  __shared__ float t[16][17];
  const float* s = blockIdx.z ? s1 : s0;
  bf16* d = blockIdx.z ? d1 : d0;
  const int x0 = blockIdx.x * 16, y0 = blockIdx.y * 16;
  t[threadIdx.y][threadIdx.x] = s[(size_t)(y0 + threadIdx.y) * 512 + x0 + threadIdx.x];
  __syncthreads();
  d[(size_t)(x0 + threadIdx.y) * 512 + (y0 + threadIdx.x)] = (bf16)t[threadIdx.x][threadIdx.y];
}

extern "C" void kernel_launch(void* const* d_in, const int* in_sizes, int n_in,
                              void* d_out, int out_size, void* d_ws, size_t ws_size,
                              hipStream_t stream) {
  const float* x     = (const float*)d_in[0];
  const float* neibs = (const float*)d_in[1];
  const float* edge  = (const float*)d_in[2];
  const int*   mask  = (const int*)d_in[3];
  const float* W1x = (const float*)d_in[4];
  const float* W2x = (const float*)d_in[5];
  const float* W1n = (const float*)d_in[6];
  const float* W2n = (const float*)d_in[7];
  const float* W1e = (const float*)d_in[8];
  const float* W2e = (const float*)d_in[9];
  const float* Wfx = (const float*)d_in[10];
  const float* bfx = (const float*)d_in[11];
  const float* Wfn = (const float*)d_in[12];
  const float* bfn = (const float*)d_in[13];
  const float* Wfe = (const float*)d_in[14];
  const float* bfe = (const float*)d_in[15];
  float* out = (float*)d_out;

  char* wsb = (char*)d_ws;
  const size_t MB = 1024 * 1024;
  bf16* W2nT = (bf16*)(wsb + 0);             // 512KB  (Wcat = [W2nT; W2eT] contiguous)
  bf16* W2eT = (bf16*)(wsb + 512 * 1024);    // 512KB
  char* wtb  = wsb + 1 * MB;                 // bf16 weights
  bf16* W1xb = (bf16*)(wtb + 0);             // 256KB
  bf16* W2xb = (bf16*)(wtb + 256 * 1024);    // 512KB
  bf16* W1nb = (bf16*)(wtb + 768 * 1024);    // 256KB
  bf16* W1eb = (bf16*)(wtb + 1024 * 1024);   // 128KB
  bf16* Wfxb = (bf16*)(wtb + 1152 * 1024);   // 128KB
  bf16* Wfnb = (bf16*)(wtb + 1280 * 1024);   // 128KB
  bf16* Wfeb = (bf16*)(wtb + 1408 * 1024);   // 64KB
  bf16* xb    = (bf16*)(wsb + 3 * MB);       // 4MB
  bf16* h_x   = (bf16*)(wsb + 7 * MB);       // 8MB
  bf16* x_att = (bf16*)(wsb + 15 * MB);      // 8MB
  bf16* ycat  = (bf16*)(wsb + 23 * MB);      // 16MB  [8192,1024] = [y_n | y_e]
  bf16* aggn  = (bf16*)(wsb + 39 * MB);      // 4MB
  bf16* agge  = (bf16*)(wsb + 43 * MB);      // 2MB

  const float inv_sqrt512 = 0.04419417382415922f;

  CvtArgs ca;
  ca.e[0] = {x,   xb,   2097152};
  ca.e[1] = {W1x, W1xb, 131072};
  ca.e[2] = {W2x, W2xb, 262144};
  ca.e[3] = {W1n, W1nb, 131072};
  ca.e[4] = {W1e, W1eb, 65536};
  ca.e[5] = {Wfx, Wfxb, 65536};
  ca.e[6] = {Wfn, Wfnb, 65536};
  ca.e[7] = {Wfe, Wfeb, 32768};
  cvt_small<<<dim3(1024, 8), 256, 0, stream>>>(ca);

  transpose2<<<dim3(32, 32, 2), dim3(16, 16), 0, stream>>>(W2n, W2nT, W2e, W2eT);

  // x MLP: h_x = tanh(x @ W1x^T); x_att = h_x @ W2x^T
  gemm64<1, bf16><<<dim3(128, 8), 256, 0, stream>>>(xb, W1xb, h_x, 256, 512, 1.f, nullptr);
  gemm64<0, bf16><<<dim3(128, 8), 256, 0, stream>>>(h_x, W2xb, x_att, 512, 512, 1.f, nullptr);
  // ycat = x_att @ [W2n | W2e]  (cols 0..511 = y_n unscaled, 512..1023 = y_e)
  gemm64<0, bf16><<<dim3(128, 16), 256, 0, stream>>>(x_att, W2nT, ycat, 512, 1024, 1.f, nullptr);

  // fused score+softmax+aggregate (neib scaled by 1/sqrt(512); edge masked)
  score_agg<256><<<2048, 256, 0, stream>>>(neibs, W1nb, ycat, 1024, 0, inv_sqrt512, nullptr, aggn);
  score_agg<128><<<2048, 256, 0, stream>>>(edge,  W1eb, ycat, 1024, 512, 1.f, mask, agge);

  // out = relu([x@Wfx^T+bfx | aggn@Wfn^T+bfn | agge@Wfe^T+bfe]), row stride 768, f32 out
  gemm64<2, float><<<dim3(128, 4), 256, 0, stream>>>(xb,   Wfxb, out + 0,   256, 768, 1.f, bfx);
  gemm64<2, float><<<dim3(128, 4), 256, 0, stream>>>(aggn, Wfnb, out + 256, 256, 768, 1.f, bfn);
  gemm64<2, float><<<dim3(128, 4), 256, 0, stream>>>(agge, Wfeb, out + 512, 128, 768, 1.f, bfe);
}

// Round 4
// 467.515 us; speedup vs baseline: 1.5546x; 1.5546x over previous
//
#include <hip/hip_runtime.h>
#include <hip/hip_bf16.h>

typedef __bf16 bf16;
typedef __bf16 bf16x2 __attribute__((ext_vector_type(2)));
typedef __bf16 bf16x4 __attribute__((ext_vector_type(4)));
typedef __bf16 bf16x8 __attribute__((ext_vector_type(8)));
typedef float  f32x4  __attribute__((ext_vector_type(4)));

// async 16B global->LDS copy. LDS dest must be wave-uniform base; HW adds lane*16.
__device__ __forceinline__ void async16(const bf16* g, bf16* l) {
  __builtin_amdgcn_global_load_lds(
      (__attribute__((address_space(1))) void*)g,
      (__attribute__((address_space(3))) void*)l,
      16, 0, 0);
}

// Hard fence + barrier: drain ALL outstanding vmem (incl. global_load_lds LDS
// writes) and lds ops BEFORE the barrier, with a full compiler memory fence so
// no staging intrinsic can be scheduled across it (nested-loop CFG safety).
__device__ __forceinline__ void fence_barrier() {
  asm volatile("s_waitcnt vmcnt(0) lgkmcnt(0)" ::: "memory");
  __syncthreads();
}

// tanh(x) = 1 - 2/(exp2(2*log2e*x)+1); v_exp_f32+v_rcp_f32, ~1e-6 abs err
__device__ __forceinline__ float fast_tanh(float x) {
  float e = __builtin_amdgcn_exp2f(x * 2.88539008177793f);
  return 1.f - 2.f * __builtin_amdgcn_rcpf(e + 1.f);
}

// Bank-conflict XOR swizzle for 16B slots on rows with >=8 slots: slot ^= row&7.
// (elem-index form).  Breaks the 16-way ds_read_b128 column-read conflict.
__device__ __forceinline__ int swz(int elem, int row) {
  return elem ^ ((row & 7) << 3);
}

// ---------------- 64x64-tile GEMM: C = act(alpha*(A@W^T)+bias) ----------------
// A:[M,K] bf16 rm, W:[N,K] bf16 rm. 256 thr = 4 waves, each 32x32 via 2x2 MFMA.
// LDS-staged (R0-proven): W/A panels re-read via L2 get bulk-prefetched per
// block; direct-from-global fragments thrash L2 under streaming (R3 lesson).
// ACT: 0 none, 1 tanh, 2 relu.  OT: bf16 or float.
template<int ACT, typename OT>
__global__ __launch_bounds__(256, 4)
void gemm64(const bf16* __restrict__ A, const bf16* __restrict__ W,
            OT* __restrict__ C, int K, int ldc, float alpha,
            const float* __restrict__ bias) {
  __shared__ bf16 As[64 * 64];
  __shared__ bf16 Bs[64 * 64];
  const int tid  = threadIdx.x;
  const int wave = tid >> 6, lane = tid & 63;
  const int wr = wave >> 1, wc = wave & 1;
  const int g = lane >> 4, l4 = lane & 15;

  f32x4 acc[2][2];
#pragma unroll
  for (int i = 0; i < 2; ++i)
#pragma unroll
    for (int j = 0; j < 2; ++j)
      acc[i][j] = (f32x4){0.f, 0.f, 0.f, 0.f};

  const bf16* Abase = A + (size_t)blockIdx.x * 64 * K;
  const bf16* Wbase = W + (size_t)blockIdx.y * 64 * K;

  for (int k0 = 0; k0 < K; k0 += 64) {
#pragma unroll
    for (int i = 0; i < 2; ++i) {          // 512 chunks of 16B per tile
      const int cb  = i * 256 + wave * 64; // wave-uniform
      const int c   = cb + lane;
      const int row = c >> 3;
      // pre-swizzled global source slot (LDS dest is linear: slot = c&7)
      const int kk  = ((c & 7) ^ (row & 7)) << 3;
      async16(Abase + (size_t)row * K + k0 + kk, &As[cb * 8]);
      async16(Wbase + (size_t)row * K + k0 + kk, &Bs[cb * 8]);
    }
    fence_barrier();
#pragma unroll
    for (int s = 0; s < 2; ++s) {
      const int koff = s * 32 + g * 8;
      bf16x8 af[2], bfr[2];
#pragma unroll
      for (int i = 0; i < 2; ++i) {
        const int ra = wr * 32 + i * 16 + l4;
        af[i] = *(const bf16x8*)&As[ra * 64 + swz(koff, ra)];
      }
#pragma unroll
      for (int j = 0; j < 2; ++j) {
        const int rb = wc * 32 + j * 16 + l4;
        bfr[j] = *(const bf16x8*)&Bs[rb * 64 + swz(koff, rb)];
      }
#pragma unroll
      for (int i = 0; i < 2; ++i)
#pragma unroll
        for (int j = 0; j < 2; ++j)
          acc[i][j] = __builtin_amdgcn_mfma_f32_16x16x32_bf16(af[i], bfr[j], acc[i][j], 0, 0, 0);
    }
    fence_barrier();
  }

  const int rbase = blockIdx.x * 64 + wr * 32;
  const int cbase = blockIdx.y * 64 + wc * 32;
#pragma unroll
  for (int i = 0; i < 2; ++i)
#pragma unroll
    for (int j = 0; j < 2; ++j) {
      const int col = cbase + j * 16 + l4;
      const float bv = bias ? bias[col] : 0.f;
#pragma unroll
      for (int r = 0; r < 4; ++r) {
        const int row = rbase + i * 16 + g * 4 + r;
        float v = acc[i][j][r] * alpha + bv;
        if (ACT == 1) v = fast_tanh(v);
        if (ACT == 2) v = fmaxf(v, 0.f);
        C[(size_t)row * ldc + col] = (OT)v;
      }
    }
}

// ---------------- fused score + softmax + aggregate (M=128 per block) --------
// Per block: 128 A-rows = 8 nodes, 512 threads = 8 waves (2 row-halves x 4
// col-quarters; acc[4][4] per wave).  Doubling M halves the total W re-stage
// traffic (1024 blocks x 256KB instead of 2048x) — the R0 limiter — while
// keeping 2 blocks/CU (LDS exactly 80KB = As 64KB + Bs 16KB) -> 4 waves/SIMD.
// W staged in 256x32 slices (16KB), R0-proven stage->fence->compute->fence.
// s[row] = scale * sum_c tanh((A@W^T)[row,c]) * y[node,c]; masked softmax over
// each node's 16 rows; agg[node,:] = sum_k w[k]*A[node*16+k,:] from LDS A-tile.
template<int D>
__global__ __launch_bounds__(512, 4)
void score_agg(const float* __restrict__ A, const bf16* __restrict__ Wb,
               const bf16* __restrict__ y, int ldy, int yoff, float scale,
               const int* __restrict__ mask, bf16* __restrict__ agg) {
  __shared__ bf16 As[128 * D];    // persistent block A-tile (bf16, swizzled) 64/32KB
  __shared__ bf16 Bs[256 * 32];   // W slice (swizzled); overlaid by sred/wgt at end
  float* sred = (float*)Bs;       // [4][128] per-colquarter row partials
  float* wgt  = (float*)Bs + 512; // [128] softmax weights
  const int tid  = threadIdx.x;
  const int wave = tid >> 6, lane = tid & 63;
  const int wr = wave >> 2, wc = wave & 3;   // row-half, col-quarter
  const int g = lane >> 4, l4 = lane & 15;
  const int blk = blockIdx.x;

  // stage one 256x32 W slice (16KB = 1024 chunks of 16B, 2/thread).
  // LDS dest linear; source slot pre-swizzled: slot' = slot ^ ((row>>1)&3)
  // -> ds_read_b128 column reads land 2-way (free) on 64B rows.
  auto stageB = [&](const bf16* Wsrc, int k) {
#pragma unroll
    for (int i = 0; i < 2; ++i) {
      const int cb  = i * 512 + wave * 64;  // wave-uniform
      const int c   = cb + lane;
      const int row = c >> 2;               // 4 chunks per 32-elem row
      const int sl  = (c & 3) ^ ((row >> 1) & 3);
      async16(Wsrc + (size_t)row * D + k + sl * 8, &Bs[cb * 8]);
    }
  };

  // issue j=0 phase-0 W stage immediately (overlaps the A-tile conversion)
  stageB(Wb, 0);

  // ---- stage full 128xD A block: f32 global -> bf16 LDS (coalesced float4) ----
  const float* Ab = A + (size_t)blk * 128 * D;
  constexpr int F4PR = D / 4;
#pragma unroll
  for (int ii = 0; ii < D / 16; ++ii) {
    const int c    = ii * 512 + tid;
    const int row  = c / F4PR;
    const int col4 = (c % F4PR) * 4;
    const float4 v = *(const float4*)(Ab + (size_t)row * D + col4);
    bf16x4 o = {(bf16)v.x, (bf16)v.y, (bf16)v.z, (bf16)v.w};
    *(bf16x4*)&As[row * D + swz(col4, row)] = o;
  }

  float p[4][4];
#pragma unroll
  for (int i = 0; i < 4; ++i)
#pragma unroll
    for (int r = 0; r < 4; ++r) p[i][r] = 0.f;

  fence_barrier();

  constexpr int NP = D / 32;               // phases per 256-col chunk
  for (int j = 0; j < 2; ++j) {            // H-chunk of 256 cols (W rows)
    f32x4 acc[4][4];
#pragma unroll
    for (int i = 0; i < 4; ++i)
#pragma unroll
      for (int jj = 0; jj < 4; ++jj)
        acc[i][jj] = (f32x4){0.f, 0.f, 0.f, 0.f};

#pragma unroll
    for (int ph = 0; ph < NP; ++ph) {
      const int ka = ph * 32 + g * 8;
      bf16x8 af[4], bfr[4];
#pragma unroll
      for (int i = 0; i < 4; ++i) {
        const int ra = wr * 64 + i * 16 + l4;
        af[i] = *(const bf16x8*)&As[ra * D + swz(ka, ra)];
      }
#pragma unroll
      for (int jj = 0; jj < 4; ++jj) {
        const int rb = wc * 64 + jj * 16 + l4;
        const int sl = g ^ ((rb >> 1) & 3);
        bfr[jj] = *(const bf16x8*)&Bs[rb * 32 + sl * 8];
      }
#pragma unroll
      for (int i = 0; i < 4; ++i)
#pragma unroll
        for (int jj = 0; jj < 4; ++jj)
          acc[i][jj] = __builtin_amdgcn_mfma_f32_16x16x32_bf16(af[i], bfr[jj], acc[i][jj], 0, 0, 0);

      fence_barrier();                     // all waves done reading Bs
      if (ph + 1 < NP) {
        stageB(Wb + (size_t)j * 256 * D, (ph + 1) * 32);
        fence_barrier();                   // next slice ready
      } else if (j == 0) {
        stageB(Wb + (size_t)256 * D, 0);
        fence_barrier();
      }
    }

    // fold chunk into per-lane score partials (row i*16.. of half wr -> node wr*4+i)
#pragma unroll
    for (int i = 0; i < 4; ++i) {
      const size_t yb = (size_t)(blk * 8 + wr * 4 + i) * ldy + yoff + j * 256 + wc * 64;
#pragma unroll
      for (int jj = 0; jj < 4; ++jj) {
        const float yv = (float)y[yb + jj * 16 + l4];
        p[i][0] += fast_tanh(acc[i][jj][0]) * yv;
        p[i][1] += fast_tanh(acc[i][jj][1]) * yv;
        p[i][2] += fast_tanh(acc[i][jj][2]) * yv;
        p[i][3] += fast_tanh(acc[i][jj][3]) * yv;
      }
    }
  }

  // reduce over the 16 l4-lanes; lane l4==0 of each g-group holds the partial
#pragma unroll
  for (int i = 0; i < 4; ++i)
#pragma unroll
    for (int r = 0; r < 4; ++r) {
      float v = p[i][r];
#pragma unroll
      for (int m = 1; m < 16; m <<= 1) v += __shfl_xor(v, m);
      p[i][r] = v;
    }
  // all waves past the final fence_barrier -> Bs region is dead; overlay sred
  if (l4 == 0) {
#pragma unroll
    for (int i = 0; i < 4; ++i)
#pragma unroll
      for (int r = 0; r < 4; ++r)
        sred[wc * 128 + wr * 64 + i * 16 + g * 4 + r] = p[i][r];
  }
  __syncthreads();

  // ---- per-node masked softmax over 16 rows (threads 0..127, rows 0..127) ----
  if (tid < 128) {
    const int node_g = blk * 8 + (tid >> 4);
    float s = (sred[tid] + sred[128 + tid] + sred[256 + tid] + sred[384 + tid]) * scale;
    if (mask) s -= 9999999.0f * (float)mask[node_g * 16 + (tid & 15)];
    float m = s;
#pragma unroll
    for (int d = 1; d < 16; d <<= 1) m = fmaxf(m, __shfl_xor(m, d));
    float e = __builtin_amdgcn_exp2f((s - m) * 1.44269504088896f);
    float sum = e;
#pragma unroll
    for (int d = 1; d < 16; d <<= 1) sum += __shfl_xor(sum, d);
    wgt[tid] = e / sum;
  }
  __syncthreads();

  // ---- aggregate from the LDS A-tile: agg[node,d] = sum_k wgt[k]*As[node*16+k, d] ----
  constexpr int EPT = D / 64;              // elems per thread (4 for D=256, 2 for D=128)
  const int n  = tid >> 6;                 // local node 0..7
  const int dl = (tid & 63) * EPT;
  float a[EPT];
#pragma unroll
  for (int e = 0; e < EPT; ++e) a[e] = 0.f;
#pragma unroll
  for (int k = 0; k < 16; ++k) {
    const float w = wgt[n * 16 + k];
    const int rk = n * 16 + k;
    if constexpr (EPT == 4) {
      bf16x4 v = *(const bf16x4*)&As[rk * D + swz(dl, rk)];
      a[0] += w * (float)v[0]; a[1] += w * (float)v[1];
      a[2] += w * (float)v[2]; a[3] += w * (float)v[3];
    } else {
      bf16x2 v = *(const bf16x2*)&As[rk * D + swz(dl, rk)];
      a[0] += w * (float)v[0]; a[1] += w * (float)v[1];
    }
  }
  if constexpr (EPT == 4) {
    bf16x4 o = {(bf16)a[0], (bf16)a[1], (bf16)a[2], (bf16)a[3]};
    *(bf16x4*)&agg[(size_t)(blk * 8 + n) * D + dl] = o;
  } else {
    bf16x2 o = {(bf16)a[0], (bf16)a[1]};
    *(bf16x2*)&agg[(size_t)(blk * 8 + n) * D + dl] = o;
  }
}

// batched f32->bf16 conversion (x + 7 weight matrices); all sizes % 2048 == 0
struct CvtEnt { const float* s; bf16* d; int n; };
struct CvtArgs { CvtEnt e[8]; };

__global__ void cvt_small(CvtArgs args) {
  const CvtEnt ent = args.e[blockIdx.y];
  const int i = blockIdx.x * 2048 + threadIdx.x * 8;
  if (i < ent.n) {
    const float4 a = *(const float4*)(ent.s + i);
    const float4 c = *(const float4*)(ent.s + i + 4);
    bf16x8 o = { (bf16)a.x, (bf16)a.y, (bf16)a.z, (bf16)a.w,
                 (bf16)c.x, (bf16)c.y, (bf16)c.z, (bf16)c.w };
    *(bf16x8*)(ent.d + i) = o;
  }
}

// fused 512x512 transpose + f32->bf16 for both W2 matrices (z selects)
__global__ void transpose2(const float* __restrict__ s0, bf16* __restrict__ d0,
                           const float* __restrict__ s1, bf16* __restrict__ d1) {
  __shared__ float t[16][17];
  const float* s = blockIdx.z ? s1 : s0;
  bf16* d = blockIdx.z ? d1 : d0;
  const int x0 = blockIdx.x * 16, y0 = blockIdx.y * 16;
  t[threadIdx.y][threadIdx.x] = s[(size_t)(y0 + threadIdx.y) * 512 + x0 + threadIdx.x];
  __syncthreads();
  d[(size_t)(x0 + threadIdx.y) * 512 + (y0 + threadIdx.x)] = (bf16)t[threadIdx.x][threadIdx.y];
}

extern "C" void kernel_launch(void* const* d_in, const int* in_sizes, int n_in,
                              void* d_out, int out_size, void* d_ws, size_t ws_size,
                              hipStream_t stream) {
  const float* x     = (const float*)d_in[0];
  const float* neibs = (const float*)d_in[1];
  const float* edge  = (const float*)d_in[2];
  const int*   mask  = (const int*)d_in[3];
  const float* W1x = (const float*)d_in[4];
  const float* W2x = (const float*)d_in[5];
  const float* W1n = (const float*)d_in[6];
  const float* W2n = (const float*)d_in[7];
  const float* W1e = (const float*)d_in[8];
  const float* W2e = (const float*)d_in[9];
  const float* Wfx = (const float*)d_in[10];
  const float* bfx = (const float*)d_in[11];
  const float* Wfn = (const float*)d_in[12];
  const float* bfn = (const float*)d_in[13];
  const float* Wfe = (const float*)d_in[14];
  const float* bfe = (const float*)d_in[15];
  float* out = (float*)d_out;

  char* wsb = (char*)d_ws;
  const size_t MB = 1024 * 1024;
  bf16* W2nT = (bf16*)(wsb + 0);             // 512KB  (Wcat = [W2nT; W2eT] contiguous)
  bf16* W2eT = (bf16*)(wsb + 512 * 1024);    // 512KB
  char* wtb  = wsb + 1 * MB;                 // bf16 weights
  bf16* W1xb = (bf16*)(wtb + 0);             // 256KB
  bf16* W2xb = (bf16*)(wtb + 256 * 1024);    // 512KB
  bf16* W1nb = (bf16*)(wtb + 768 * 1024);    // 256KB
  bf16* W1eb = (bf16*)(wtb + 1024 * 1024);   // 128KB
  bf16* Wfxb = (bf16*)(wtb + 1152 * 1024);   // 128KB
  bf16* Wfnb = (bf16*)(wtb + 1280 * 1024);   // 128KB
  bf16* Wfeb = (bf16*)(wtb + 1408 * 1024);   // 64KB
  bf16* xb    = (bf16*)(wsb + 3 * MB);       // 4MB
  bf16* h_x   = (bf16*)(wsb + 7 * MB);       // 8MB
  bf16* x_att = (bf16*)(wsb + 15 * MB);      // 8MB
  bf16* ycat  = (bf16*)(wsb + 23 * MB);      // 16MB  [8192,1024] = [y_n | y_e]
  bf16* aggn  = (bf16*)(wsb + 39 * MB);      // 4MB
  bf16* agge  = (bf16*)(wsb + 43 * MB);      // 2MB

  const float inv_sqrt512 = 0.04419417382415922f;

  CvtArgs ca;
  ca.e[0] = {x,   xb,   2097152};
  ca.e[1] = {W1x, W1xb, 131072};
  ca.e[2] = {W2x, W2xb, 262144};
  ca.e[3] = {W1n, W1nb, 131072};
  ca.e[4] = {W1e, W1eb, 65536};
  ca.e[5] = {Wfx, Wfxb, 65536};
  ca.e[6] = {Wfn, Wfnb, 65536};
  ca.e[7] = {Wfe, Wfeb, 32768};
  cvt_small<<<dim3(1024, 8), 256, 0, stream>>>(ca);

  transpose2<<<dim3(32, 32, 2), dim3(16, 16), 0, stream>>>(W2n, W2nT, W2e, W2eT);

  // x MLP: h_x = tanh(x @ W1x^T); x_att = h_x @ W2x^T
  gemm64<1, bf16><<<dim3(128, 8), 256, 0, stream>>>(xb, W1xb, h_x, 256, 512, 1.f, nullptr);
  gemm64<0, bf16><<<dim3(128, 8), 256, 0, stream>>>(h_x, W2xb, x_att, 512, 512, 1.f, nullptr);
  // ycat = x_att @ [W2n | W2e]  (cols 0..511 = y_n unscaled, 512..1023 = y_e)
  gemm64<0, bf16><<<dim3(128, 16), 256, 0, stream>>>(x_att, W2nT, ycat, 512, 1024, 1.f, nullptr);

  // fused score+softmax+aggregate (neib scaled by 1/sqrt(512); edge masked)
  score_agg<256><<<1024, 512, 0, stream>>>(neibs, W1nb, ycat, 1024, 0, inv_sqrt512, nullptr, aggn);
  score_agg<128><<<1024, 512, 0, stream>>>(edge,  W1eb, ycat, 1024, 512, 1.f, mask, agge);

  // out = relu([x@Wfx^T+bfx | aggn@Wfn^T+bfn | agge@Wfe^T+bfe]), row stride 768, f32 out
  gemm64<2, float><<<dim3(128, 4), 256, 0, stream>>>(xb,   Wfxb, out + 0,   256, 768, 1.f, bfx);
  gemm64<2, float><<<dim3(128, 4), 256, 0, stream>>>(aggn, Wfnb, out + 256, 256, 768, 1.f, bfn);
  gemm64<2, float><<<dim3(128, 4), 256, 0, stream>>>(agge, Wfeb, out + 512, 128, 768, 1.f, bfe);
}

// Round 5
// 395.513 us; speedup vs baseline: 1.8377x; 1.1820x over previous
//
#include <hip/hip_runtime.h>
#include <hip/hip_bf16.h>

typedef __bf16 bf16;
typedef __bf16 bf16x2 __attribute__((ext_vector_type(2)));
typedef __bf16 bf16x4 __attribute__((ext_vector_type(4)));
typedef __bf16 bf16x8 __attribute__((ext_vector_type(8)));
typedef float  f32x4  __attribute__((ext_vector_type(4)));

// async 16B global->LDS copy. LDS dest must be wave-uniform base; HW adds lane*16.
__device__ __forceinline__ void async16(const bf16* g, bf16* l) {
  __builtin_amdgcn_global_load_lds(
      (__attribute__((address_space(1))) void*)g,
      (__attribute__((address_space(3))) void*)l,
      16, 0, 0);
}

// Counted vmem wait (T4): wait until at most N vmem ops outstanding.  With a
// double-buffered stage issued one phase ahead, N = loads-per-stage leaves the
// newest stage in flight while guaranteeing the previous one has landed.
template<int N>
__device__ __forceinline__ void vm_wait() {
  asm volatile("s_waitcnt vmcnt(%0)" :: "i"(N) : "memory");
}

// Raw barrier with compiler memory fences (NO vmcnt(0) drain — that is the
// point; __syncthreads() emits a full drain and defeats counted vmcnt).
__device__ __forceinline__ void hard_barrier() {
  asm volatile("" ::: "memory");
  __builtin_amdgcn_s_barrier();
  asm volatile("" ::: "memory");
}

// Full drain + barrier: prologue only (orders VALU ds_writes + stage loads).
__device__ __forceinline__ void fence_barrier() {
  asm volatile("s_waitcnt vmcnt(0) lgkmcnt(0)" ::: "memory");
  __syncthreads();
}

// tanh(x) = 1 - 2/(exp2(2*log2e*x)+1); v_exp_f32+v_rcp_f32, ~1e-6 abs err
__device__ __forceinline__ float fast_tanh(float x) {
  float e = __builtin_amdgcn_exp2f(x * 2.88539008177793f);
  return 1.f - 2.f * __builtin_amdgcn_rcpf(e + 1.f);
}

// Bank-conflict XOR swizzle for 16B slots on rows with >=8 slots: slot ^= row&7.
// Breaks the 16-way ds_read_b128 column-read conflict (elem-index form).
__device__ __forceinline__ int swz(int elem, int row) {
  return elem ^ ((row & 7) << 3);
}

// ---------------- 64x64-tile GEMM: C = act(alpha*(A@W^T)+bias) ----------------
// A:[M,K] bf16 rm, W:[N,K] bf16 rm. 256 thr = 4 waves, each 32x32 via 2x2 MFMA.
// Double-buffered LDS (32KB, 4 blocks/CU); stage(t+1) issued before compute(t),
// waited with counted vmcnt(4) so the new stage stays in flight across compute.
// ACT: 0 none, 1 tanh, 2 relu.  OT: bf16 or float.
template<int ACT, typename OT>
__global__ __launch_bounds__(256, 4)
void gemm64(const bf16* __restrict__ A, const bf16* __restrict__ W,
            OT* __restrict__ C, int K, int ldc, float alpha,
            const float* __restrict__ bias) {
  __shared__ bf16 As[2][64 * 64];
  __shared__ bf16 Bs[2][64 * 64];
  const int tid  = threadIdx.x;
  const int wave = tid >> 6, lane = tid & 63;
  const int wr = wave >> 1, wc = wave & 1;
  const int g = lane >> 4, l4 = lane & 15;

  f32x4 acc[2][2];
#pragma unroll
  for (int i = 0; i < 2; ++i)
#pragma unroll
    for (int j = 0; j < 2; ++j)
      acc[i][j] = (f32x4){0.f, 0.f, 0.f, 0.f};

  const bf16* Abase = A + (size_t)blockIdx.x * 64 * K;
  const bf16* Wbase = W + (size_t)blockIdx.y * 64 * K;

  auto stage = [&](int buf, int k0) {      // 4 loads/thread
#pragma unroll
    for (int i = 0; i < 2; ++i) {          // 512 chunks of 16B per tile
      const int cb  = i * 256 + wave * 64; // wave-uniform
      const int c   = cb + lane;
      const int row = c >> 3;
      // pre-swizzled global source slot (LDS dest is linear: slot = c&7)
      const int kk  = ((c & 7) ^ (row & 7)) << 3;
      async16(Abase + (size_t)row * K + k0 + kk, &As[buf][cb * 8]);
      async16(Wbase + (size_t)row * K + k0 + kk, &Bs[buf][cb * 8]);
    }
  };

  const int nt = K >> 6;                   // K is a multiple of 64
  stage(0, 0);
  for (int t = 0; t < nt; ++t) {
    const int buf = t & 1;
    if (t + 1 < nt) { stage(buf ^ 1, (t + 1) * 64); vm_wait<4>(); }
    else            { vm_wait<0>(); }
    hard_barrier();                        // buf fully staged for all waves
#pragma unroll
    for (int s = 0; s < 2; ++s) {
      const int koff = s * 32 + g * 8;
      bf16x8 af[2], bfr[2];
#pragma unroll
      for (int i = 0; i < 2; ++i) {
        const int ra = wr * 32 + i * 16 + l4;
        af[i] = *(const bf16x8*)&As[buf][ra * 64 + swz(koff, ra)];
      }
#pragma unroll
      for (int j = 0; j < 2; ++j) {
        const int rb = wc * 32 + j * 16 + l4;
        bfr[j] = *(const bf16x8*)&Bs[buf][rb * 64 + swz(koff, rb)];
      }
#pragma unroll
      for (int i = 0; i < 2; ++i)
#pragma unroll
        for (int j = 0; j < 2; ++j)
          acc[i][j] = __builtin_amdgcn_mfma_f32_16x16x32_bf16(af[i], bfr[j], acc[i][j], 0, 0, 0);
    }
    hard_barrier();                        // all waves done reading buf
  }

  const int rbase = blockIdx.x * 64 + wr * 32;
  const int cbase = blockIdx.y * 64 + wc * 32;
#pragma unroll
  for (int i = 0; i < 2; ++i)
#pragma unroll
    for (int j = 0; j < 2; ++j) {
      const int col = cbase + j * 16 + l4;
      const float bv = bias ? bias[col] : 0.f;
#pragma unroll
      for (int r = 0; r < 4; ++r) {
        const int row = rbase + i * 16 + g * 4 + r;
        float v = acc[i][j][r] * alpha + bv;
        if (ACT == 1) v = fast_tanh(v);
        if (ACT == 2) v = fmaxf(v, 0.f);
        C[(size_t)row * ldc + col] = (OT)v;
      }
    }
}

// ---------------- fused score + softmax + aggregate ----------------
// Per block: 64 A-rows = 4 nodes (R0-proven shape: 256 thr, launch_bounds
// (256,2) -> 256-VGPR cap, NO spill; R3/R4 showed (.,4)'s 128 cap spills
// ~70MB/dispatch of scratch).  s[row] = scale*sum_c tanh((A@W^T)[row,c])*
// y[node,c]; masked softmax over each node's 16 rows; agg[node,:] =
// sum_k w[k]*A[node*16+k,:] from the persistent LDS A-tile.
// W staged in double-buffered 256x32 slices (2x16KB; LDS total 64KB -> 2
// blocks/CU): stage slice s+1, vm_wait<4> (drains slice s only), raw barrier,
// compute, raw barrier.  Stage loads for s+1 remain in flight across compute.
template<int D>
__global__ __launch_bounds__(256, 2)
void score_agg(const float* __restrict__ A, const bf16* __restrict__ Wb,
               const bf16* __restrict__ y, int ldy, int yoff, float scale,
               const int* __restrict__ mask, bf16* __restrict__ agg) {
  __shared__ bf16 As[64 * D];      // persistent block A-tile (bf16, swizzled)
  __shared__ bf16 Bs[2][256 * 32]; // W slices; overlaid by sred/wgt at the end
  float* sred = (float*)(&Bs[0][0]);       // [4][64] per-wave row partials
  float* wgt  = (float*)(&Bs[0][0]) + 256; // [64] softmax weights
  const int tid  = threadIdx.x;
  const int wave = tid >> 6, lane = tid & 63;
  const int g = lane >> 4, l4 = lane & 15;
  const int blk = blockIdx.x;

  constexpr int NP = D / 32;       // slices per 256-col chunk
  constexpr int NS = 2 * NP;       // total slices

  // stage one 256x32 W slice (16KB = 1024 chunks of 16B, 4/thread).
  // LDS dest linear; source slot pre-swizzled: slot' = slot ^ ((row>>1)&3)
  // -> ds_read_b128 column reads land 2-way (free) on 64B rows.
  auto stageB = [&](int s, int buf) {
    const int j  = s / NP, ph = s % NP;
    const bf16* Wsrc = Wb + (size_t)j * 256 * D + ph * 32;
#pragma unroll
    for (int i = 0; i < 4; ++i) {
      const int cb  = i * 256 + wave * 64; // wave-uniform
      const int c   = cb + lane;
      const int row = c >> 2;              // 4 chunks per 32-elem row
      const int sl  = (c & 3) ^ ((row >> 1) & 3);
      async16(Wsrc + (size_t)row * D + sl * 8, &Bs[buf][cb * 8]);
    }
  };

  // prologue: issue slice 0 stage; it overlaps the A-tile conversion
  stageB(0, 0);

  // ---- stage full 64xD A block: f32 global -> bf16 LDS (coalesced float4) ----
  const float* Ab = A + (size_t)blk * 64 * D;
  constexpr int F4PR = D / 4;
#pragma unroll
  for (int ii = 0; ii < D / 16; ++ii) {
    const int c    = ii * 256 + tid;
    const int row  = c / F4PR;
    const int col4 = (c % F4PR) * 4;
    const float4 v = *(const float4*)(Ab + (size_t)row * D + col4);
    bf16x4 o = {(bf16)v.x, (bf16)v.y, (bf16)v.z, (bf16)v.w};
    *(bf16x4*)&As[row * D + swz(col4, row)] = o;
  }

  float p[4][4];
#pragma unroll
  for (int i = 0; i < 4; ++i)
#pragma unroll
    for (int r = 0; r < 4; ++r) p[i][r] = 0.f;

  fence_barrier();   // drains prologue stage + conversion ds_writes

  int s = 0;
  for (int j = 0; j < 2; ++j) {            // H-chunk of 256 cols (W rows)
    f32x4 acc[4][4];
#pragma unroll
    for (int i = 0; i < 4; ++i)
#pragma unroll
      for (int jj = 0; jj < 4; ++jj)
        acc[i][jj] = (f32x4){0.f, 0.f, 0.f, 0.f};

#pragma unroll
    for (int ph = 0; ph < NP; ++ph) {
      const int buf = s & 1;
      if (s + 1 < NS) { stageB(s + 1, buf ^ 1); vm_wait<4>(); }
      else            { vm_wait<0>(); }
      hard_barrier();                      // slice s staged for all waves

      const int ka = ph * 32 + g * 8;
      bf16x8 af[4], bfr[4];
#pragma unroll
      for (int i = 0; i < 4; ++i) {
        const int ra = i * 16 + l4;
        af[i] = *(const bf16x8*)&As[ra * D + swz(ka, ra)];
      }
#pragma unroll
      for (int jj = 0; jj < 4; ++jj) {
        const int rb = wave * 64 + jj * 16 + l4;
        const int sl = g ^ ((rb >> 1) & 3);
        bfr[jj] = *(const bf16x8*)&Bs[buf][rb * 32 + sl * 8];
      }
#pragma unroll
      for (int i = 0; i < 4; ++i)
#pragma unroll
        for (int jj = 0; jj < 4; ++jj)
          acc[i][jj] = __builtin_amdgcn_mfma_f32_16x16x32_bf16(af[i], bfr[jj], acc[i][jj], 0, 0, 0);

      hard_barrier();                      // all waves done reading slice s
      ++s;
    }

    // fold chunk into per-lane score partials (rows i*16.. all belong to node i)
#pragma unroll
    for (int i = 0; i < 4; ++i) {
      const size_t yb = (size_t)(blk * 4 + i) * ldy + yoff + j * 256 + wave * 64;
#pragma unroll
      for (int jj = 0; jj < 4; ++jj) {
        const float yv = (float)y[yb + jj * 16 + l4];
        p[i][0] += fast_tanh(acc[i][jj][0]) * yv;
        p[i][1] += fast_tanh(acc[i][jj][1]) * yv;
        p[i][2] += fast_tanh(acc[i][jj][2]) * yv;
        p[i][3] += fast_tanh(acc[i][jj][3]) * yv;
      }
    }
  }

  // reduce over the 16 l4-lanes; lane l4==0 of each g-group holds the partial
#pragma unroll
  for (int i = 0; i < 4; ++i)
#pragma unroll
    for (int r = 0; r < 4; ++r) {
      float v = p[i][r];
#pragma unroll
      for (int m = 1; m < 16; m <<= 1) v += __shfl_xor(v, m);
      p[i][r] = v;
    }
  // all waves past the last slice barrier -> Bs region is dead; overlay sred
  if (l4 == 0) {
#pragma unroll
    for (int i = 0; i < 4; ++i)
#pragma unroll
      for (int r = 0; r < 4; ++r)
        sred[wave * 64 + i * 16 + g * 4 + r] = p[i][r];
  }
  __syncthreads();

  // ---- per-node masked softmax over 16 rows (threads 0..63 = wave 0) ----
  if (tid < 64) {
    const int node_g = blk * 4 + (tid >> 4);
    float sv = (sred[tid] + sred[64 + tid] + sred[128 + tid] + sred[192 + tid]) * scale;
    if (mask) sv -= 9999999.0f * (float)mask[node_g * 16 + (tid & 15)];
    float m = sv;
#pragma unroll
    for (int d = 1; d < 16; d <<= 1) m = fmaxf(m, __shfl_xor(m, d));
    float e = __builtin_amdgcn_exp2f((sv - m) * 1.44269504088896f);
    float sum = e;
#pragma unroll
    for (int d = 1; d < 16; d <<= 1) sum += __shfl_xor(sum, d);
    wgt[tid] = e / sum;
  }
  __syncthreads();

  // ---- aggregate from the LDS A-tile: agg[node,d] = sum_k wgt[k]*As[node*16+k, d] ----
  constexpr int EPT = D / 64;              // elems per thread (4 for D=256, 2 for D=128)
  const int n  = tid >> 6;                 // local node
  const int dl = (tid & 63) * EPT;
  float a[EPT];
#pragma unroll
  for (int e = 0; e < EPT; ++e) a[e] = 0.f;
#pragma unroll
  for (int k = 0; k < 16; ++k) {
    const float w = wgt[n * 16 + k];
    const int rk = n * 16 + k;
    if constexpr (EPT == 4) {
      bf16x4 v = *(const bf16x4*)&As[rk * D + swz(dl, rk)];
      a[0] += w * (float)v[0]; a[1] += w * (float)v[1];
      a[2] += w * (float)v[2]; a[3] += w * (float)v[3];
    } else {
      bf16x2 v = *(const bf16x2*)&As[rk * D + swz(dl, rk)];
      a[0] += w * (float)v[0]; a[1] += w * (float)v[1];
    }
  }
  if constexpr (EPT == 4) {
    bf16x4 o = {(bf16)a[0], (bf16)a[1], (bf16)a[2], (bf16)a[3]};
    *(bf16x4*)&agg[(size_t)(blk * 4 + n) * D + dl] = o;
  } else {
    bf16x2 o = {(bf16)a[0], (bf16)a[1]};
    *(bf16x2*)&agg[(size_t)(blk * 4 + n) * D + dl] = o;
  }
}

// batched f32->bf16 conversion (x + 7 weight matrices); all sizes % 2048 == 0
struct CvtEnt { const float* s; bf16* d; int n; };
struct CvtArgs { CvtEnt e[8]; };

__global__ void cvt_small(CvtArgs args) {
  const CvtEnt ent = args.e[blockIdx.y];
  const int i = blockIdx.x * 2048 + threadIdx.x * 8;
  if (i < ent.n) {
    const float4 a = *(const float4*)(ent.s + i);
    const float4 c = *(const float4*)(ent.s + i + 4);
    bf16x8 o = { (bf16)a.x, (bf16)a.y, (bf16)a.z, (bf16)a.w,
                 (bf16)c.x, (bf16)c.y, (bf16)c.z, (bf16)c.w };
    *(bf16x8*)(ent.d + i) = o;
  }
}

// fused 512x512 transpose + f32->bf16 for both W2 matrices (z selects)
__global__ void transpose2(const float* __restrict__ s0, bf16* __restrict__ d0,
                           const float* __restrict__ s1, bf16* __restrict__ d1) {
  __shared__ float t[16][17];
  const float* s = blockIdx.z ? s1 : s0;
  bf16* d = blockIdx.z ? d1 : d0;
  const int x0 = blockIdx.x * 16, y0 = blockIdx.y * 16;
  t[threadIdx.y][threadIdx.x] = s[(size_t)(y0 + threadIdx.y) * 512 + x0 + threadIdx.x];
  __syncthreads();
  d[(size_t)(x0 + threadIdx.y) * 512 + (y0 + threadIdx.x)] = (bf16)t[threadIdx.x][threadIdx.y];
}

extern "C" void kernel_launch(void* const* d_in, const int* in_sizes, int n_in,
                              void* d_out, int out_size, void* d_ws, size_t ws_size,
                              hipStream_t stream) {
  const float* x     = (const float*)d_in[0];
  const float* neibs = (const float*)d_in[1];
  const float* edge  = (const float*)d_in[2];
  const int*   mask  = (const int*)d_in[3];
  const float* W1x = (const float*)d_in[4];
  const float* W2x = (const float*)d_in[5];
  const float* W1n = (const float*)d_in[6];
  const float* W2n = (const float*)d_in[7];
  const float* W1e = (const float*)d_in[8];
  const float* W2e = (const float*)d_in[9];
  const float* Wfx = (const float*)d_in[10];
  const float* bfx = (const float*)d_in[11];
  const float* Wfn = (const float*)d_in[12];
  const float* bfn = (const float*)d_in[13];
  const float* Wfe = (const float*)d_in[14];
  const float* bfe = (const float*)d_in[15];
  float* out = (float*)d_out;

  char* wsb = (char*)d_ws;
  const size_t MB = 1024 * 1024;
  bf16* W2nT = (bf16*)(wsb + 0);             // 512KB  (Wcat = [W2nT; W2eT] contiguous)
  bf16* W2eT = (bf16*)(wsb + 512 * 1024);    // 512KB
  char* wtb  = wsb + 1 * MB;                 // bf16 weights
  bf16* W1xb = (bf16*)(wtb + 0);             // 256KB
  bf16* W2xb = (bf16*)(wtb + 256 * 1024);    // 512KB
  bf16* W1nb = (bf16*)(wtb + 768 * 1024);    // 256KB
  bf16* W1eb = (bf16*)(wtb + 1024 * 1024);   // 128KB
  bf16* Wfxb = (bf16*)(wtb + 1152 * 1024);   // 128KB
  bf16* Wfnb = (bf16*)(wtb + 1280 * 1024);   // 128KB
  bf16* Wfeb = (bf16*)(wtb + 1408 * 1024);   // 64KB
  bf16* xb    = (bf16*)(wsb + 3 * MB);       // 4MB
  bf16* h_x   = (bf16*)(wsb + 7 * MB);       // 8MB
  bf16* x_att = (bf16*)(wsb + 15 * MB);      // 8MB
  bf16* ycat  = (bf16*)(wsb + 23 * MB);      // 16MB  [8192,1024] = [y_n | y_e]
  bf16* aggn  = (bf16*)(wsb + 39 * MB);      // 4MB
  bf16* agge  = (bf16*)(wsb + 43 * MB);      // 2MB

  const float inv_sqrt512 = 0.04419417382415922f;

  CvtArgs ca;
  ca.e[0] = {x,   xb,   2097152};
  ca.e[1] = {W1x, W1xb, 131072};
  ca.e[2] = {W2x, W2xb, 262144};
  ca.e[3] = {W1n, W1nb, 131072};
  ca.e[4] = {W1e, W1eb, 65536};
  ca.e[5] = {Wfx, Wfxb, 65536};
  ca.e[6] = {Wfn, Wfnb, 65536};
  ca.e[7] = {Wfe, Wfeb, 32768};
  cvt_small<<<dim3(1024, 8), 256, 0, stream>>>(ca);

  transpose2<<<dim3(32, 32, 2), dim3(16, 16), 0, stream>>>(W2n, W2nT, W2e, W2eT);

  // x MLP: h_x = tanh(x @ W1x^T); x_att = h_x @ W2x^T
  gemm64<1, bf16><<<dim3(128, 8), 256, 0, stream>>>(xb, W1xb, h_x, 256, 512, 1.f, nullptr);
  gemm64<0, bf16><<<dim3(128, 8), 256, 0, stream>>>(h_x, W2xb, x_att, 512, 512, 1.f, nullptr);
  // ycat = x_att @ [W2n | W2e]  (cols 0..511 = y_n unscaled, 512..1023 = y_e)
  gemm64<0, bf16><<<dim3(128, 16), 256, 0, stream>>>(x_att, W2nT, ycat, 512, 1024, 1.f, nullptr);

  // fused score+softmax+aggregate (neib scaled by 1/sqrt(512); edge masked)
  score_agg<256><<<2048, 256, 0, stream>>>(neibs, W1nb, ycat, 1024, 0, inv_sqrt512, nullptr, aggn);
  score_agg<128><<<2048, 256, 0, stream>>>(edge,  W1eb, ycat, 1024, 512, 1.f, mask, agge);

  // out = relu([x@Wfx^T+bfx | aggn@Wfn^T+bfn | agge@Wfe^T+bfe]), row stride 768, f32 out
  gemm64<2, float><<<dim3(128, 4), 256, 0, stream>>>(xb,   Wfxb, out + 0,   256, 768, 1.f, bfx);
  gemm64<2, float><<<dim3(128, 4), 256, 0, stream>>>(aggn, Wfnb, out + 256, 256, 768, 1.f, bfn);
  gemm64<2, float><<<dim3(128, 4), 256, 0, stream>>>(agge, Wfeb, out + 512, 128, 768, 1.f, bfe);
}

// Round 6
// 385.632 us; speedup vs baseline: 1.8847x; 1.0256x over previous
//
#include <hip/hip_runtime.h>
#include <hip/hip_bf16.h>

typedef __bf16 bf16;
typedef __bf16 bf16x2 __attribute__((ext_vector_type(2)));
typedef __bf16 bf16x4 __attribute__((ext_vector_type(4)));
typedef __bf16 bf16x8 __attribute__((ext_vector_type(8)));
typedef float  f32x4  __attribute__((ext_vector_type(4)));

// async 16B global->LDS copy. LDS dest must be wave-uniform base; HW adds lane*16.
__device__ __forceinline__ void async16(const bf16* g, bf16* l) {
  __builtin_amdgcn_global_load_lds(
      (__attribute__((address_space(1))) void*)g,
      (__attribute__((address_space(3))) void*)l,
      16, 0, 0);
}

// Counted vmem wait (T4): wait until at most N vmem ops outstanding.
template<int N>
__device__ __forceinline__ void vm_wait() {
  asm volatile("s_waitcnt vmcnt(%0)" :: "i"(N) : "memory");
}

// Raw barrier with compiler memory fences (no vmcnt(0) drain).
__device__ __forceinline__ void hard_barrier() {
  asm volatile("" ::: "memory");
  __builtin_amdgcn_s_barrier();
  asm volatile("" ::: "memory");
}

// Full drain + barrier: prologue only (orders VALU ds_writes + stage loads).
__device__ __forceinline__ void fence_barrier() {
  asm volatile("s_waitcnt vmcnt(0) lgkmcnt(0)" ::: "memory");
  __syncthreads();
}

// tanh(x) = 1 - 2/(exp2(2*log2e*x)+1); v_exp_f32+v_rcp_f32, ~1e-6 abs err
__device__ __forceinline__ float fast_tanh(float x) {
  float e = __builtin_amdgcn_exp2f(x * 2.88539008177793f);
  return 1.f - 2.f * __builtin_amdgcn_rcpf(e + 1.f);
}

// Bank-conflict XOR swizzle for 16B slots on rows with >=8 slots: slot ^= row&7.
__device__ __forceinline__ int swz(int elem, int row) {
  return elem ^ ((row & 7) << 3);
}

// ---------------- 64x64-tile GEMM core: C = act(alpha*(A@W^T)+bias) ----------
// A:[M,K] bf16 rm, W:[N,K] bf16 rm. 256 thr = 4 waves, each 32x32 via 2x2 MFMA.
// Double-buffered LDS; counted vmcnt(4); T5 setprio around MFMA clusters.
template<int ACT, typename OT>
__device__ __forceinline__
void gemm64_body(const bf16* __restrict__ A, const bf16* __restrict__ W,
                 OT* __restrict__ C, int K, int ldc, float alpha,
                 const float* __restrict__ bias,
                 int bx, int by, bf16* As /*2*64*64*/, bf16* Bs /*2*64*64*/) {
  const int tid  = threadIdx.x;
  const int wave = tid >> 6, lane = tid & 63;
  const int wr = wave >> 1, wc = wave & 1;
  const int g = lane >> 4, l4 = lane & 15;

  f32x4 acc[2][2];
#pragma unroll
  for (int i = 0; i < 2; ++i)
#pragma unroll
    for (int j = 0; j < 2; ++j)
      acc[i][j] = (f32x4){0.f, 0.f, 0.f, 0.f};

  const bf16* Abase = A + (size_t)bx * 64 * K;
  const bf16* Wbase = W + (size_t)by * 64 * K;

  auto stage = [&](int buf, int k0) {      // 4 loads/thread
#pragma unroll
    for (int i = 0; i < 2; ++i) {          // 512 chunks of 16B per tile
      const int cb  = i * 256 + wave * 64; // wave-uniform
      const int c   = cb + lane;
      const int row = c >> 3;
      const int kk  = ((c & 7) ^ (row & 7)) << 3;  // pre-swizzled source slot
      async16(Abase + (size_t)row * K + k0 + kk, &As[buf * 4096 + cb * 8]);
      async16(Wbase + (size_t)row * K + k0 + kk, &Bs[buf * 4096 + cb * 8]);
    }
  };

  const int nt = K >> 6;                   // K is a multiple of 64
  stage(0, 0);
  for (int t = 0; t < nt; ++t) {
    const int buf = t & 1;
    if (t + 1 < nt) { stage(buf ^ 1, (t + 1) * 64); vm_wait<4>(); }
    else            { vm_wait<0>(); }
    hard_barrier();                        // buf fully staged for all waves
#pragma unroll
    for (int s = 0; s < 2; ++s) {
      const int koff = s * 32 + g * 8;
      bf16x8 af[2], bfr[2];
#pragma unroll
      for (int i = 0; i < 2; ++i) {
        const int ra = wr * 32 + i * 16 + l4;
        af[i] = *(const bf16x8*)&As[buf * 4096 + ra * 64 + swz(koff, ra)];
      }
#pragma unroll
      for (int j = 0; j < 2; ++j) {
        const int rb = wc * 32 + j * 16 + l4;
        bfr[j] = *(const bf16x8*)&Bs[buf * 4096 + rb * 64 + swz(koff, rb)];
      }
      __builtin_amdgcn_s_setprio(1);
#pragma unroll
      for (int i = 0; i < 2; ++i)
#pragma unroll
        for (int j = 0; j < 2; ++j)
          acc[i][j] = __builtin_amdgcn_mfma_f32_16x16x32_bf16(af[i], bfr[j], acc[i][j], 0, 0, 0);
      __builtin_amdgcn_s_setprio(0);
    }
    hard_barrier();                        // all waves done reading buf
  }

  const int rbase = bx * 64 + wr * 32;
  const int cbase = by * 64 + wc * 32;
#pragma unroll
  for (int i = 0; i < 2; ++i)
#pragma unroll
    for (int j = 0; j < 2; ++j) {
      const int col = cbase + j * 16 + l4;
      const float bv = bias ? bias[col] : 0.f;
#pragma unroll
      for (int r = 0; r < 4; ++r) {
        const int row = rbase + i * 16 + g * 4 + r;
        float v = acc[i][j][r] * alpha + bv;
        if (ACT == 1) v = fast_tanh(v);
        if (ACT == 2) v = fmaxf(v, 0.f);
        C[(size_t)row * ldc + col] = (OT)v;
      }
    }
}

template<int ACT, typename OT>
__global__ __launch_bounds__(256, 4)
void gemm64(const bf16* __restrict__ A, const bf16* __restrict__ W,
            OT* __restrict__ C, int K, int ldc, float alpha,
            const float* __restrict__ bias) {
  __shared__ bf16 As[2 * 64 * 64];
  __shared__ bf16 Bs[2 * 64 * 64];
  gemm64_body<ACT, OT>(A, W, C, K, ldc, alpha, bias, blockIdx.x, blockIdx.y, As, Bs);
}

// fused tail: three independent relu-GEMMs into out (row stride 768), z selects
struct TailEnt { const bf16* A; const bf16* W; const float* bias; int K; int coff; };
struct TailArgs { TailEnt e[3]; };

__global__ __launch_bounds__(256, 4)
void gemm64_tail(TailArgs args, float* __restrict__ out) {
  __shared__ bf16 As[2 * 64 * 64];
  __shared__ bf16 Bs[2 * 64 * 64];
  const TailEnt ent = args.e[blockIdx.z];
  gemm64_body<2, float>(ent.A, ent.W, out + ent.coff, ent.K, 768, 1.f, ent.bias,
                        blockIdx.x, blockIdx.y, As, Bs);
}

// ---------------- fused score + softmax + aggregate ----------------
// Per block: 64 A-rows = 4 nodes (256 thr, (256,2) -> no spill).
// s[row] = scale*sum_c tanh((A@W^T)[row,c])*y[node,c]; masked softmax over each
// node's 16 rows; agg[node,:] = sum_k w[k]*A[node*16+k,:] from LDS A-tile.
// W double-buffered 256x32 slices; counted vmcnt(4); setprio on MFMA cluster.
// y for BOTH chunks preloaded before the prologue fence (hidden under A-conv).
template<int D>
__global__ __launch_bounds__(256, 2)
void score_agg(const float* __restrict__ A, const bf16* __restrict__ Wb,
               const bf16* __restrict__ y, int ldy, int yoff, float scale,
               const int* __restrict__ mask, bf16* __restrict__ agg) {
  __shared__ bf16 As[64 * D];      // persistent block A-tile (bf16, swizzled)
  __shared__ bf16 Bs[2][256 * 32]; // W slices; overlaid by sred/wgt at the end
  float* sred = (float*)(&Bs[0][0]);       // [4][64] per-wave row partials
  float* wgt  = (float*)(&Bs[0][0]) + 256; // [64] softmax weights
  const int tid  = threadIdx.x;
  const int wave = tid >> 6, lane = tid & 63;
  const int g = lane >> 4, l4 = lane & 15;
  const int blk = blockIdx.x;

  constexpr int NP = D / 32;       // slices per 256-col chunk
  constexpr int NS = 2 * NP;       // total slices

  auto stageB = [&](int s, int buf) {      // 4 loads/thread, 16KB slice
    const int j  = s / NP, ph = s % NP;
    const bf16* Wsrc = Wb + (size_t)j * 256 * D + ph * 32;
#pragma unroll
    for (int i = 0; i < 4; ++i) {
      const int cb  = i * 256 + wave * 64; // wave-uniform
      const int c   = cb + lane;
      const int row = c >> 2;              // 4 chunks per 32-elem row
      const int sl  = (c & 3) ^ ((row >> 1) & 3);  // 2-way-free read swizzle
      async16(Wsrc + (size_t)row * D + sl * 8, &Bs[buf][cb * 8]);
    }
  };

  // prologue: issue slice 0 stage; overlaps A-tile conversion + y preload
  stageB(0, 0);

  // ---- preload y for both chunks (32 f32 regs); drained by prologue fence ----
  float yv[2][4][4];
#pragma unroll
  for (int j = 0; j < 2; ++j)
#pragma unroll
    for (int i = 0; i < 4; ++i) {
      const size_t yb = (size_t)(blk * 4 + i) * ldy + yoff + j * 256 + wave * 64;
#pragma unroll
      for (int jj = 0; jj < 4; ++jj)
        yv[j][i][jj] = (float)y[yb + jj * 16 + l4];
    }

  // ---- stage full 64xD A block: f32 global -> bf16 LDS (coalesced float4) ----
  const float* Ab = A + (size_t)blk * 64 * D;
  constexpr int F4PR = D / 4;
#pragma unroll
  for (int ii = 0; ii < D / 16; ++ii) {
    const int c    = ii * 256 + tid;
    const int row  = c / F4PR;
    const int col4 = (c % F4PR) * 4;
    const float4 v = *(const float4*)(Ab + (size_t)row * D + col4);
    bf16x4 o = {(bf16)v.x, (bf16)v.y, (bf16)v.z, (bf16)v.w};
    *(bf16x4*)&As[row * D + swz(col4, row)] = o;
  }

  float p[4][4];
#pragma unroll
  for (int i = 0; i < 4; ++i)
#pragma unroll
    for (int r = 0; r < 4; ++r) p[i][r] = 0.f;

  fence_barrier();   // drains prologue stage + y loads + conversion ds_writes

  int s = 0;
  for (int j = 0; j < 2; ++j) {            // H-chunk of 256 cols (W rows)
    f32x4 acc[4][4];
#pragma unroll
    for (int i = 0; i < 4; ++i)
#pragma unroll
      for (int jj = 0; jj < 4; ++jj)
        acc[i][jj] = (f32x4){0.f, 0.f, 0.f, 0.f};

#pragma unroll
    for (int ph = 0; ph < NP; ++ph) {
      const int buf = s & 1;
      if (s + 1 < NS) { stageB(s + 1, buf ^ 1); vm_wait<4>(); }
      else            { vm_wait<0>(); }
      hard_barrier();                      // slice s staged for all waves

      const int ka = ph * 32 + g * 8;
      bf16x8 af[4], bfr[4];
#pragma unroll
      for (int i = 0; i < 4; ++i) {
        const int ra = i * 16 + l4;
        af[i] = *(const bf16x8*)&As[ra * D + swz(ka, ra)];
      }
#pragma unroll
      for (int jj = 0; jj < 4; ++jj) {
        const int rb = wave * 64 + jj * 16 + l4;
        const int sl = g ^ ((rb >> 1) & 3);
        bfr[jj] = *(const bf16x8*)&Bs[buf][rb * 32 + sl * 8];
      }
      __builtin_amdgcn_s_setprio(1);
#pragma unroll
      for (int i = 0; i < 4; ++i)
#pragma unroll
        for (int jj = 0; jj < 4; ++jj)
          acc[i][jj] = __builtin_amdgcn_mfma_f32_16x16x32_bf16(af[i], bfr[jj], acc[i][jj], 0, 0, 0);
      __builtin_amdgcn_s_setprio(0);

      hard_barrier();                      // all waves done reading slice s
      ++s;
    }

    // fold chunk into per-lane score partials (rows i*16.. all belong to node i)
#pragma unroll
    for (int i = 0; i < 4; ++i) {
#pragma unroll
      for (int jj = 0; jj < 4; ++jj) {
        const float yvv = yv[j][i][jj];
        p[i][0] += fast_tanh(acc[i][jj][0]) * yvv;
        p[i][1] += fast_tanh(acc[i][jj][1]) * yvv;
        p[i][2] += fast_tanh(acc[i][jj][2]) * yvv;
        p[i][3] += fast_tanh(acc[i][jj][3]) * yvv;
      }
    }
  }

  // reduce over the 16 l4-lanes; lane l4==0 of each g-group holds the partial
#pragma unroll
  for (int i = 0; i < 4; ++i)
#pragma unroll
    for (int r = 0; r < 4; ++r) {
      float v = p[i][r];
#pragma unroll
      for (int m = 1; m < 16; m <<= 1) v += __shfl_xor(v, m);
      p[i][r] = v;
    }
  // all waves past the last slice barrier -> Bs region is dead; overlay sred
  if (l4 == 0) {
#pragma unroll
    for (int i = 0; i < 4; ++i)
#pragma unroll
      for (int r = 0; r < 4; ++r)
        sred[wave * 64 + i * 16 + g * 4 + r] = p[i][r];
  }
  __syncthreads();

  // ---- per-node masked softmax over 16 rows (threads 0..63 = wave 0) ----
  if (tid < 64) {
    const int node_g = blk * 4 + (tid >> 4);
    float sv = (sred[tid] + sred[64 + tid] + sred[128 + tid] + sred[192 + tid]) * scale;
    if (mask) sv -= 9999999.0f * (float)mask[node_g * 16 + (tid & 15)];
    float m = sv;
#pragma unroll
    for (int d = 1; d < 16; d <<= 1) m = fmaxf(m, __shfl_xor(m, d));
    float e = __builtin_amdgcn_exp2f((sv - m) * 1.44269504088896f);
    float sum = e;
#pragma unroll
    for (int d = 1; d < 16; d <<= 1) sum += __shfl_xor(sum, d);
    wgt[tid] = e / sum;
  }
  __syncthreads();

  // ---- aggregate from the LDS A-tile: agg[node,d] = sum_k wgt[k]*As[node*16+k, d] ----
  constexpr int EPT = D / 64;              // elems per thread
  const int n  = tid >> 6;                 // local node
  const int dl = (tid & 63) * EPT;
  float a[EPT];
#pragma unroll
  for (int e = 0; e < EPT; ++e) a[e] = 0.f;
#pragma unroll
  for (int k = 0; k < 16; ++k) {
    const float w = wgt[n * 16 + k];
    const int rk = n * 16 + k;
    if constexpr (EPT == 4) {
      bf16x4 v = *(const bf16x4*)&As[rk * D + swz(dl, rk)];
      a[0] += w * (float)v[0]; a[1] += w * (float)v[1];
      a[2] += w * (float)v[2]; a[3] += w * (float)v[3];
    } else {
      bf16x2 v = *(const bf16x2*)&As[rk * D + swz(dl, rk)];
      a[0] += w * (float)v[0]; a[1] += w * (float)v[1];
    }
  }
  if constexpr (EPT == 4) {
    bf16x4 o = {(bf16)a[0], (bf16)a[1], (bf16)a[2], (bf16)a[3]};
    *(bf16x4*)&agg[(size_t)(blk * 4 + n) * D + dl] = o;
  } else {
    bf16x2 o = {(bf16)a[0], (bf16)a[1]};
    *(bf16x2*)&agg[(size_t)(blk * 4 + n) * D + dl] = o;
  }
}

// fused prologue: batched f32->bf16 conversion (y=0..7) + 512x512 transpose
// of both W2 matrices (y==8; two z-tiles per block).  All cvt sizes % 2048 == 0.
struct CvtEnt { const float* s; bf16* d; int n; };
struct CvtArgs {
  CvtEnt e[8];
  const float* t0s; bf16* t0d;     // W2n -> W2nT
  const float* t1s; bf16* t1d;     // W2e -> W2eT
};

__global__ void prologue(CvtArgs args) {
  if (blockIdx.y < 8) {
    const CvtEnt ent = args.e[blockIdx.y];
    const int i = blockIdx.x * 2048 + threadIdx.x * 8;
    if (i < ent.n) {
      const float4 a = *(const float4*)(ent.s + i);
      const float4 c = *(const float4*)(ent.s + i + 4);
      bf16x8 o = { (bf16)a.x, (bf16)a.y, (bf16)a.z, (bf16)a.w,
                   (bf16)c.x, (bf16)c.y, (bf16)c.z, (bf16)c.w };
      *(bf16x8*)(ent.d + i) = o;
    }
  } else {
    __shared__ float t[16][17];
    const int tx = threadIdx.x & 15, ty = threadIdx.x >> 4;
    const int x0 = (blockIdx.x & 31) * 16, y0 = (blockIdx.x >> 5) * 16;
#pragma unroll
    for (int z = 0; z < 2; ++z) {
      const float* s = z ? args.t1s : args.t0s;
      bf16* d = z ? args.t1d : args.t0d;
      t[ty][tx] = s[(size_t)(y0 + ty) * 512 + x0 + tx];
      __syncthreads();
      d[(size_t)(x0 + ty) * 512 + (y0 + tx)] = (bf16)t[tx][ty];
      __syncthreads();
    }
  }
}

extern "C" void kernel_launch(void* const* d_in, const int* in_sizes, int n_in,
                              void* d_out, int out_size, void* d_ws, size_t ws_size,
                              hipStream_t stream) {
  const float* x     = (const float*)d_in[0];
  const float* neibs = (const float*)d_in[1];
  const float* edge  = (const float*)d_in[2];
  const int*   mask  = (const int*)d_in[3];
  const float* W1x = (const float*)d_in[4];
  const float* W2x = (const float*)d_in[5];
  const float* W1n = (const float*)d_in[6];
  const float* W2n = (const float*)d_in[7];
  const float* W1e = (const float*)d_in[8];
  const float* W2e = (const float*)d_in[9];
  const float* Wfx = (const float*)d_in[10];
  const float* bfx = (const float*)d_in[11];
  const float* Wfn = (const float*)d_in[12];
  const float* bfn = (const float*)d_in[13];
  const float* Wfe = (const float*)d_in[14];
  const float* bfe = (const float*)d_in[15];
  float* out = (float*)d_out;

  char* wsb = (char*)d_ws;
  const size_t MB = 1024 * 1024;
  bf16* W2nT = (bf16*)(wsb + 0);             // 512KB  (Wcat = [W2nT; W2eT] contiguous)
  bf16* W2eT = (bf16*)(wsb + 512 * 1024);    // 512KB
  char* wtb  = wsb + 1 * MB;                 // bf16 weights
  bf16* W1xb = (bf16*)(wtb + 0);             // 256KB
  bf16* W2xb = (bf16*)(wtb + 256 * 1024);    // 512KB
  bf16* W1nb = (bf16*)(wtb + 768 * 1024);    // 256KB
  bf16* W1eb = (bf16*)(wtb + 1024 * 1024);   // 128KB
  bf16* Wfxb = (bf16*)(wtb + 1152 * 1024);   // 128KB
  bf16* Wfnb = (bf16*)(wtb + 1280 * 1024);   // 128KB
  bf16* Wfeb = (bf16*)(wtb + 1408 * 1024);   // 64KB
  bf16* xb    = (bf16*)(wsb + 3 * MB);       // 4MB
  bf16* h_x   = (bf16*)(wsb + 7 * MB);       // 8MB
  bf16* x_att = (bf16*)(wsb + 15 * MB);      // 8MB
  bf16* ycat  = (bf16*)(wsb + 23 * MB);      // 16MB  [8192,1024] = [y_n | y_e]
  bf16* aggn  = (bf16*)(wsb + 39 * MB);      // 4MB
  bf16* agge  = (bf16*)(wsb + 43 * MB);      // 2MB

  const float inv_sqrt512 = 0.04419417382415922f;

  CvtArgs ca;
  ca.e[0] = {x,   xb,   2097152};
  ca.e[1] = {W1x, W1xb, 131072};
  ca.e[2] = {W2x, W2xb, 262144};
  ca.e[3] = {W1n, W1nb, 131072};
  ca.e[4] = {W1e, W1eb, 65536};
  ca.e[5] = {Wfx, Wfxb, 65536};
  ca.e[6] = {Wfn, Wfnb, 65536};
  ca.e[7] = {Wfe, Wfeb, 32768};
  ca.t0s = W2n; ca.t0d = W2nT;
  ca.t1s = W2e; ca.t1d = W2eT;
  prologue<<<dim3(1024, 9), 256, 0, stream>>>(ca);

  // x MLP: h_x = tanh(x @ W1x^T); x_att = h_x @ W2x^T
  gemm64<1, bf16><<<dim3(128, 8), 256, 0, stream>>>(xb, W1xb, h_x, 256, 512, 1.f, nullptr);
  gemm64<0, bf16><<<dim3(128, 8), 256, 0, stream>>>(h_x, W2xb, x_att, 512, 512, 1.f, nullptr);
  // ycat = x_att @ [W2n | W2e]  (cols 0..511 = y_n unscaled, 512..1023 = y_e)
  gemm64<0, bf16><<<dim3(128, 16), 256, 0, stream>>>(x_att, W2nT, ycat, 512, 1024, 1.f, nullptr);

  // fused score+softmax+aggregate (neib scaled by 1/sqrt(512); edge masked)
  score_agg<256><<<2048, 256, 0, stream>>>(neibs, W1nb, ycat, 1024, 0, inv_sqrt512, nullptr, aggn);
  score_agg<128><<<2048, 256, 0, stream>>>(edge,  W1eb, ycat, 1024, 512, 1.f, mask, agge);

  // out = relu([x@Wfx^T+bfx | aggn@Wfn^T+bfn | agge@Wfe^T+bfe]), one fused launch
  TailArgs ta;
  ta.e[0] = {xb,   Wfxb, bfx, 256, 0};
  ta.e[1] = {aggn, Wfnb, bfn, 256, 256};
  ta.e[2] = {agge, Wfeb, bfe, 128, 512};
  gemm64_tail<<<dim3(128, 4, 3), 256, 0, stream>>>(ta, out);
}